// Round 1
// baseline (100120.837 us; speedup 1.0000x reference)
//
#include <hip/hip_runtime.h>
#include <hip/hip_fp16.h>

#define T_LEN 262144
#define HID 32

// ---- tiny intrinsic wrappers -------------------------------------------------
__device__ __forceinline__ float rl_f(float v, int lane) {
    return __int_as_float(__builtin_amdgcn_readlane(__float_as_int(v), lane));
}

#if defined(__has_builtin)
#if __has_builtin(__builtin_amdgcn_exp2f)
#define FEXP2(x) __builtin_amdgcn_exp2f(x)
#endif
#endif
#ifndef FEXP2
#define FEXP2(x) exp2f(x)
#endif

__device__ __forceinline__ float frcp(float x) { return __builtin_amdgcn_rcpf(x); }

#define L2E 1.4426950408889634f

// ---- scan kernel: 1 block, 64 threads ---------------------------------------
// Lane l owns gate rows r0 = l (i-rows 0..31 / f-rows 32..63) and
// r1 = 64+l (g-rows 64..95 / o-rows 96..127).
// All weights/biases prescaled by -log2(e) (g-rows by -2*log2(e)) so that
// sigmoid(x) = rcp(1 + exp2(acc)) and tanh(g) = fma(rcp(1+exp2(acc)), 2, -1).
template <bool STORE_HS>
__global__ __launch_bounds__(64, 1) void lstm_scan(
    const float* __restrict__ x,      // [T,3]
    const float* __restrict__ W_ih,   // [128,3]
    const float* __restrict__ W_hh,   // [128,32]
    const float* __restrict__ b_ih,   // [128]
    const float* __restrict__ b_hh,   // [128]
    const float* __restrict__ W_lin,  // [1,32]  (fallback path only)
    const float* __restrict__ b_lin,  // [1]
    float* __restrict__ hs,           // ws: [T/4][32] float4   (STORE_HS)
    float* __restrict__ out)          // [T]                    (!STORE_HS)
{
    const int l = threadIdx.x;        // 0..63
    const bool lo = (l < 32);
    const int r0 = l;
    const int r1 = 64 + l;
    const float s0 = -L2E;
    const float s1 = lo ? -2.0f * L2E : -L2E;
    const float m1 = lo ? 2.0f : 1.0f;   // post-act: tanh needs 2*sig-1
    const float d1 = lo ? -1.0f : 0.0f;

    // preload + prescale recurrent weights: 64 VGPRs
    float w0[HID], w1[HID];
#pragma unroll
    for (int j = 0; j < HID; ++j) {
        w0[j] = W_hh[r0 * HID + j] * s0;
        w1[j] = W_hh[r1 * HID + j] * s1;
    }
    const float wi00 = W_ih[r0 * 3 + 0] * s0, wi01 = W_ih[r0 * 3 + 1] * s0,
                wi02 = W_ih[r0 * 3 + 2] * s0;
    const float wi10 = W_ih[r1 * 3 + 0] * s1, wi11 = W_ih[r1 * 3 + 1] * s1,
                wi12 = W_ih[r1 * 3 + 2] * s1;
    const float bb0 = (b_ih[r0] + b_hh[r0]) * s0;
    const float bb1 = (b_ih[r1] + b_hh[r1]) * s1;

    // fallback-path constants: out[t] = b + sum over 64 lanes of h*0.5*W_lin[j]
    const float wl2 = STORE_HS ? 0.0f : (0.5f * W_lin[l & 31]);
    const float bl = STORE_HS ? 0.0f : b_lin[0];

    float h = 0.0f, c = 0.0f;
    float hh0 = 0.0f, hh1 = 0.0f, hh2 = 0.0f;
    float4* hs4 = (float4*)hs;

    // x double-buffer: lane u holds x[t0+u][0..2]
    float xa, xb, xc;
    {
        const float* xp = x + l * 3;
        xa = xp[0]; xb = xp[1]; xc = xp[2];
    }

    for (int t0 = 0; t0 < T_LEN; t0 += 64) {
        // prefetch next 64 x rows (consumed 64 steps from now)
        int tn = t0 + 64;
        if (tn >= T_LEN) tn = 0;  // harmless dummy prefetch on last block
        const float* xp = x + (tn + l) * 3;
        float xna = xp[0], xnb = xp[1], xnc = xp[2];

#pragma unroll 4
        for (int u = 0; u < 64; ++u) {
            // off-chain: x contribution (bias already folded, prescaled)
            const float xs0 = rl_f(xa, u), xs1 = rl_f(xb, u), xs2 = rl_f(xc, u);
            float acc0 = fmaf(wi02, xs2, fmaf(wi01, xs1, fmaf(wi00, xs0, bb0)));
            float acc1 = fmaf(wi12, xs2, fmaf(wi11, xs1, fmaf(wi10, xs0, bb1)));

            // recurrent matvec: broadcast h[j] from lane j, 2 rows per lane
#pragma unroll
            for (int j = 0; j < HID; ++j) {
                const float hj = rl_f(h, j);
                acc0 = fmaf(w0[j], hj, acc0);
                acc1 = fmaf(w1[j], hj, acc1);
            }

            // activations (weights prescaled: acc = -log2e * gate)
            const float a0 = frcp(1.0f + FEXP2(acc0));            // sigmoid(i|f)
            const float rr = frcp(1.0f + FEXP2(acc1));
            const float a1 = fmaf(rr, m1, d1);                    // tanh(g) | sigmoid(o)

            // exchange halves: lanes<32 have (i, tanh g); lanes>=32 have (f, o)
            const float xa0 = __shfl_xor(a0, 32, 64);
            const float xa1 = __shfl_xor(a1, 32, 64);
            const float f_ = lo ? xa0 : a0;
            const float ig = lo ? a0 * a1 : xa0 * xa1;
            const float o_ = lo ? xa1 : a1;

            c = fmaf(f_, c, ig);
            const float tc =
                fmaf(frcp(1.0f + FEXP2(-2.0f * L2E * c)), 2.0f, -1.0f);  // tanh(c)
            h = o_ * tc;  // lanes l and l+32 both hold h[l&31]

            if (STORE_HS) {
                const int ph = u & 3;
                if (ph == 0) hh0 = h;
                else if (ph == 1) hh1 = h;
                else if (ph == 2) hh2 = h;
                else if (lo) {
                    const int t4 = (t0 + u) >> 2;
                    hs4[t4 * 32 + l] = make_float4(hh0, hh1, hh2, h);
                }
            } else {
                // in-wave reduction for out[t] (ws-too-small fallback)
                float p = h * wl2;
                p += __shfl_xor(p, 1, 64);
                p += __shfl_xor(p, 2, 64);
                p += __shfl_xor(p, 4, 64);
                p += __shfl_xor(p, 8, 64);
                p += __shfl_xor(p, 16, 64);
                p += __shfl_xor(p, 32, 64);
                if (l == 0) out[t0 + u] = p + bl;
            }
        }

        xa = xna; xb = xnb; xc = xnc;
    }
}

// ---- output GEMV: out[t] = b_lin + sum_j W_lin[j] * h[t][j] ------------------
// hs layout: [t>>2][j][t&3] floats (float4 per (t4,j))
__global__ __launch_bounds__(256) void lstm_out(
    const float* __restrict__ hs, const float* __restrict__ W_lin,
    const float* __restrict__ b_lin, float* __restrict__ out)
{
    const int t = blockIdx.x * blockDim.x + threadIdx.x;
    if (t >= T_LEN) return;
    const int t4 = t >> 2, ph = t & 3;
    const float* base = hs + (size_t)t4 * 128 + ph;
    float acc = b_lin[0];
#pragma unroll
    for (int j = 0; j < HID; ++j) acc = fmaf(W_lin[j], base[j * 4], acc);
    out[t] = acc;
}

extern "C" void kernel_launch(void* const* d_in, const int* in_sizes, int n_in,
                              void* d_out, int out_size, void* d_ws, size_t ws_size,
                              hipStream_t stream) {
    const float* x = (const float*)d_in[0];
    const float* W_ih = (const float*)d_in[1];
    const float* W_hh = (const float*)d_in[2];
    const float* b_ih = (const float*)d_in[3];
    const float* b_hh = (const float*)d_in[4];
    const float* W_lin = (const float*)d_in[5];
    const float* b_lin = (const float*)d_in[6];
    float* out = (float*)d_out;

    const size_t hs_bytes = (size_t)(T_LEN / 4) * 32 * sizeof(float4);  // 32 MiB
    if (ws_size >= hs_bytes) {
        float* hs = (float*)d_ws;
        hipLaunchKernelGGL((lstm_scan<true>), dim3(1), dim3(64), 0, stream,
                           x, W_ih, W_hh, b_ih, b_hh, W_lin, b_lin, hs, out);
        hipLaunchKernelGGL(lstm_out, dim3(T_LEN / 256), dim3(256), 0, stream,
                           hs, W_lin, b_lin, out);
    } else {
        hipLaunchKernelGGL((lstm_scan<false>), dim3(1), dim3(64), 0, stream,
                           x, W_ih, W_hh, b_ih, b_hh, W_lin, b_lin, nullptr, out);
    }
}

// Round 2
// 62667.572 us; speedup vs baseline: 1.5976x; 1.5976x over previous
//
#include <hip/hip_runtime.h>
#include <hip/hip_fp16.h>

#define T_LEN 262144
#define HID 32

// ---- tiny intrinsic wrappers -------------------------------------------------
__device__ __forceinline__ float rl_f(float v, int lane) {
    return __int_as_float(__builtin_amdgcn_readlane(__float_as_int(v), lane));
}

#if defined(__has_builtin)
#if __has_builtin(__builtin_amdgcn_exp2f)
#define FEXP2(x) __builtin_amdgcn_exp2f(x)
#endif
#endif
#ifndef FEXP2
#define FEXP2(x) exp2f(x)
#endif

__device__ __forceinline__ float frcp(float x) { return __builtin_amdgcn_rcpf(x); }

#define L2E 1.4426950408889634f
#define KN2 (-2.0f * L2E)

typedef unsigned int uint2_ev __attribute__((ext_vector_type(2)));

// value held by lane (l ^ 32) — VALU permlane on gfx950, LDS-shuffle fallback
__device__ __forceinline__ float swap32(float v) {
#if defined(__has_builtin) && __has_builtin(__builtin_amdgcn_permlane32_swap)
    uint2_ev r = __builtin_amdgcn_permlane32_swap(__float_as_uint(v),
                                                  __float_as_uint(v), false, false);
    // r.x: lanes32-63 = v[l-32]   r.y: lanes0-31 = v[l+32]
    return __uint_as_float((threadIdx.x & 32) ? r.x : r.y);
#else
    return __shfl_xor(v, 32, 64);
#endif
}

// ---- repetition macros: named scalar weights (NO indexed arrays -> no scratch)
#define REP32(M) M(0) M(1) M(2) M(3) M(4) M(5) M(6) M(7) \
                 M(8) M(9) M(10) M(11) M(12) M(13) M(14) M(15) \
                 M(16) M(17) M(18) M(19) M(20) M(21) M(22) M(23) \
                 M(24) M(25) M(26) M(27) M(28) M(29) M(30) M(31)

#define DECLW(j) float w0_##j, w1_##j;
#define LOADW(j) w0_##j = W_hh[r0 * HID + j] * s0; \
                 w1_##j = W_hh[r1 * HID + j] * s1;

// one MAC pair, round-robin over 4 accumulators (breaks the serial FMA chain)
#define MAC(j, A) { const float hj_##j = rl_f(h, j); \
                    acc0_##A = fmaf(w0_##j, hj_##j, acc0_##A); \
                    acc1_##A = fmaf(w1_##j, hj_##j, acc1_##A); }

#define MATVEC \
    MAC(0,0) MAC(1,1) MAC(2,2) MAC(3,3)  MAC(4,0) MAC(5,1) MAC(6,2) MAC(7,3) \
    MAC(8,0) MAC(9,1) MAC(10,2) MAC(11,3) MAC(12,0) MAC(13,1) MAC(14,2) MAC(15,3) \
    MAC(16,0) MAC(17,1) MAC(18,2) MAC(19,3) MAC(20,0) MAC(21,1) MAC(22,2) MAC(23,3) \
    MAC(24,0) MAC(25,1) MAC(26,2) MAC(27,3) MAC(28,0) MAC(29,1) MAC(30,2) MAC(31,3)

// ---- scan kernel: 1 block, 64 threads ---------------------------------------
// Lane l owns gate rows r0 = l (i rows 0..31 / f rows 32..63) and
// r1 = 64+l (g rows 64..95 / o rows 96..127).
// Weights/biases prescaled by -log2(e) (g rows by -2*log2(e)) so
// sigmoid = rcp(1+exp2(acc)), tanh(g) = 2*rcp(1+exp2(acc))-1.
// Cell state kept as c2 = -2*log2(e)*c so tanh(c) = 2*rcp(1+exp2(c2))-1
// with no multiply on the dependency chain.
template <bool STORE_HS>
__global__ __launch_bounds__(64, 1) void lstm_scan(
    const float* __restrict__ x,      // [T,3]
    const float* __restrict__ W_ih,   // [128,3]
    const float* __restrict__ W_hh,   // [128,32]
    const float* __restrict__ b_ih,   // [128]
    const float* __restrict__ b_hh,   // [128]
    const float* __restrict__ W_lin,  // [1,32]  (fallback path only)
    const float* __restrict__ b_lin,  // [1]
    float* __restrict__ hs,           // ws: [T/4][32] float4   (STORE_HS)
    float* __restrict__ out)          // [T]                    (!STORE_HS)
{
    const int l = threadIdx.x;        // 0..63
    const bool lo = (l < 32);
    const int r0 = l;
    const int r1 = 64 + l;
    const float s0 = -L2E;
    const float s1 = lo ? KN2 : -L2E;
    const float m1 = lo ? 2.0f : 1.0f;   // tanh(g) = 2*sig-1 on lo lanes
    const float d1 = lo ? -1.0f : 0.0f;

    REP32(DECLW)
    REP32(LOADW)

    const float wi00 = W_ih[r0 * 3 + 0] * s0, wi01 = W_ih[r0 * 3 + 1] * s0,
                wi02 = W_ih[r0 * 3 + 2] * s0;
    const float wi10 = W_ih[r1 * 3 + 0] * s1, wi11 = W_ih[r1 * 3 + 1] * s1,
                wi12 = W_ih[r1 * 3 + 2] * s1;
    const float bb0 = (b_ih[r0] + b_hh[r0]) * s0;
    const float bb1 = (b_ih[r1] + b_hh[r1]) * s1;

    // fallback-path constants
    const float wl2 = STORE_HS ? 0.0f : (0.5f * W_lin[l & 31]);
    const float bl = STORE_HS ? 0.0f : b_lin[0];

    float h = 0.0f, c2 = 0.0f;        // c2 = -2*log2e * c ; c0 = 0
    float hh0 = 0.0f, hh1 = 0.0f, hh2 = 0.0f;
    float4* hs4 = (float4*)hs;

    // x double-buffer: lane u holds x[t0+u][0..2]
    float xa, xb, xc;
    {
        const float* xp = x + l * 3;
        xa = xp[0]; xb = xp[1]; xc = xp[2];
    }

    for (int t0 = 0; t0 < T_LEN; t0 += 64) {
        int tn = t0 + 64;
        if (tn >= T_LEN) tn = 0;      // harmless dummy prefetch on last block
        const float* xp = x + (tn + l) * 3;
        float xna = xp[0], xnb = xp[1], xnc = xp[2];

#pragma unroll 4
        for (int u = 0; u < 64; ++u) {
            // x contribution, spread across the 4 accumulators
            const float xs0 = rl_f(xa, u), xs1 = rl_f(xb, u), xs2 = rl_f(xc, u);
            float acc0_0 = fmaf(wi00, xs0, bb0);
            float acc0_1 = wi01 * xs1;
            float acc0_2 = wi02 * xs2;
            float acc0_3 = 0.0f;
            float acc1_0 = fmaf(wi10, xs0, bb1);
            float acc1_1 = wi11 * xs1;
            float acc1_2 = wi12 * xs2;
            float acc1_3 = 0.0f;

            MATVEC

            const float acc0 = (acc0_0 + acc0_1) + (acc0_2 + acc0_3);
            const float acc1 = (acc1_0 + acc1_1) + (acc1_2 + acc1_3);

            // activations
            const float a0 = frcp(1.0f + FEXP2(acc0));   // sigmoid(i) | sigmoid(f)
            const float rr = frcp(1.0f + FEXP2(acc1));
            const float a1 = fmaf(rr, m1, d1);           // tanh(g) | sigmoid(o)

            // cross-half exchange (VALU permlane, not LDS)
            const float sa0 = swap32(a0);
            const float sa1 = swap32(a1);
            const float f_ = lo ? sa0 : a0;
            const float i_ = lo ? a0 : sa0;
            const float g_ = lo ? a1 : sa1;
            const float o_ = lo ? sa1 : a1;

            const float igK = (i_ * KN2) * g_;
            c2 = fmaf(f_, c2, igK);
            const float tc = fmaf(frcp(1.0f + FEXP2(c2)), 2.0f, -1.0f);  // tanh(c)
            h = o_ * tc;              // lanes l and l+32 both hold h[l&31]

            if (STORE_HS) {
                const int ph = u & 3;
                if (ph == 0) hh0 = h;
                else if (ph == 1) hh1 = h;
                else if (ph == 2) hh2 = h;
                else if (lo) {
                    const int t4 = (t0 + u) >> 2;
                    hs4[t4 * 32 + l] = make_float4(hh0, hh1, hh2, h);
                }
            } else {
                float p = h * wl2;
                p += __shfl_xor(p, 1, 64);
                p += __shfl_xor(p, 2, 64);
                p += __shfl_xor(p, 4, 64);
                p += __shfl_xor(p, 8, 64);
                p += __shfl_xor(p, 16, 64);
                p += __shfl_xor(p, 32, 64);
                if (l == 0) out[t0 + u] = p + bl;
            }
        }

        xa = xna; xb = xnb; xc = xnc;
    }
}

// ---- output GEMV: out[t] = b_lin + sum_j W_lin[j] * h[t][j] ------------------
__global__ __launch_bounds__(256) void lstm_out(
    const float* __restrict__ hs, const float* __restrict__ W_lin,
    const float* __restrict__ b_lin, float* __restrict__ out)
{
    const int t = blockIdx.x * blockDim.x + threadIdx.x;
    if (t >= T_LEN) return;
    const int t4 = t >> 2, ph = t & 3;
    const float* base = hs + (size_t)t4 * 128 + ph;
    float acc = b_lin[0];
#pragma unroll
    for (int j = 0; j < HID; ++j) acc = fmaf(W_lin[j], base[j * 4], acc);
    out[t] = acc;
}

extern "C" void kernel_launch(void* const* d_in, const int* in_sizes, int n_in,
                              void* d_out, int out_size, void* d_ws, size_t ws_size,
                              hipStream_t stream) {
    const float* x = (const float*)d_in[0];
    const float* W_ih = (const float*)d_in[1];
    const float* W_hh = (const float*)d_in[2];
    const float* b_ih = (const float*)d_in[3];
    const float* b_hh = (const float*)d_in[4];
    const float* W_lin = (const float*)d_in[5];
    const float* b_lin = (const float*)d_in[6];
    float* out = (float*)d_out;

    const size_t hs_bytes = (size_t)(T_LEN / 4) * 32 * sizeof(float4);  // 32 MiB
    if (ws_size >= hs_bytes) {
        float* hs = (float*)d_ws;
        hipLaunchKernelGGL((lstm_scan<true>), dim3(1), dim3(64), 0, stream,
                           x, W_ih, W_hh, b_ih, b_hh, W_lin, b_lin, hs, out);
        hipLaunchKernelGGL(lstm_out, dim3(T_LEN / 256), dim3(256), 0, stream,
                           hs, W_lin, b_lin, out);
    } else {
        hipLaunchKernelGGL((lstm_scan<false>), dim3(1), dim3(64), 0, stream,
                           x, W_ih, W_hh, b_ih, b_hh, W_lin, b_lin, nullptr, out);
    }
}

// Round 3
// 62271.301 us; speedup vs baseline: 1.6078x; 1.0064x over previous
//
#include <hip/hip_runtime.h>
#include <hip/hip_fp16.h>

#define T_LEN 262144
#define HID 32

// ---- tiny intrinsic wrappers -------------------------------------------------
__device__ __forceinline__ float rl_f(float v, int lane) {
    return __int_as_float(__builtin_amdgcn_readlane(__float_as_int(v), lane));
}

#if defined(__has_builtin)
#if __has_builtin(__builtin_amdgcn_exp2f)
#define FEXP2(x) __builtin_amdgcn_exp2f(x)
#endif
#endif
#ifndef FEXP2
#define FEXP2(x) exp2f(x)
#endif

__device__ __forceinline__ float frcp(float x) { return __builtin_amdgcn_rcpf(x); }

#define L2E 1.4426950408889634f
#define KN2 (-2.0f * L2E)

typedef unsigned int uint2_ev __attribute__((ext_vector_type(2)));

// value held by lane (l ^ 32) — VALU permlane on gfx950, LDS-shuffle fallback
__device__ __forceinline__ float swap32(float v) {
#if defined(__has_builtin) && __has_builtin(__builtin_amdgcn_permlane32_swap)
    uint2_ev r = __builtin_amdgcn_permlane32_swap(__float_as_uint(v),
                                                  __float_as_uint(v), false, false);
    return __uint_as_float((threadIdx.x & 32) ? r.x : r.y);
#else
    return __shfl_xor(v, 32, 64);
#endif
}

// ---- repetition macros: named scalar weights --------------------------------
#define REP32(M) M(0) M(1) M(2) M(3) M(4) M(5) M(6) M(7) \
                 M(8) M(9) M(10) M(11) M(12) M(13) M(14) M(15) \
                 M(16) M(17) M(18) M(19) M(20) M(21) M(22) M(23) \
                 M(24) M(25) M(26) M(27) M(28) M(29) M(30) M(31)

#define DECLW(j) float w0_##j, w1_##j;
#define LOADW(j) w0_##j = W_hh[r0 * HID + j] * s0; \
                 w1_##j = W_hh[r1 * HID + j] * s1;

// Zero-instruction register pin: "+v" makes each value an asm output, so the
// compiler can no longer re-derive it by reloading from memory -> the 64
// weights become loop-carried VGPR-resident values.
#define PIN8(a,b,c,d,e,f,g,h_) \
    asm("" : "+v"(a), "+v"(b), "+v"(c), "+v"(d), \
             "+v"(e), "+v"(f), "+v"(g), "+v"(h_));
#define PIN_W0_A PIN8(w0_0,w0_1,w0_2,w0_3,w0_4,w0_5,w0_6,w0_7)
#define PIN_W0_B PIN8(w0_8,w0_9,w0_10,w0_11,w0_12,w0_13,w0_14,w0_15)
#define PIN_W0_C PIN8(w0_16,w0_17,w0_18,w0_19,w0_20,w0_21,w0_22,w0_23)
#define PIN_W0_D PIN8(w0_24,w0_25,w0_26,w0_27,w0_28,w0_29,w0_30,w0_31)
#define PIN_W1_A PIN8(w1_0,w1_1,w1_2,w1_3,w1_4,w1_5,w1_6,w1_7)
#define PIN_W1_B PIN8(w1_8,w1_9,w1_10,w1_11,w1_12,w1_13,w1_14,w1_15)
#define PIN_W1_C PIN8(w1_16,w1_17,w1_18,w1_19,w1_20,w1_21,w1_22,w1_23)
#define PIN_W1_D PIN8(w1_24,w1_25,w1_26,w1_27,w1_28,w1_29,w1_30,w1_31)
#define PIN_ALL PIN_W0_A PIN_W0_B PIN_W0_C PIN_W0_D \
                PIN_W1_A PIN_W1_B PIN_W1_C PIN_W1_D \
                PIN8(wi00,wi01,wi02,wi10,wi11,wi12,bb0,bb1)

// one MAC pair, round-robin over 4 accumulators (breaks the serial FMA chain)
#define MAC(j, A) { const float hj_##j = rl_f(h, j); \
                    acc0_##A = fmaf(w0_##j, hj_##j, acc0_##A); \
                    acc1_##A = fmaf(w1_##j, hj_##j, acc1_##A); }

#define MATVEC \
    MAC(0,0) MAC(1,1) MAC(2,2) MAC(3,3)  MAC(4,0) MAC(5,1) MAC(6,2) MAC(7,3) \
    MAC(8,0) MAC(9,1) MAC(10,2) MAC(11,3) MAC(12,0) MAC(13,1) MAC(14,2) MAC(15,3) \
    MAC(16,0) MAC(17,1) MAC(18,2) MAC(19,3) MAC(20,0) MAC(21,1) MAC(22,2) MAC(23,3) \
    MAC(24,0) MAC(25,1) MAC(26,2) MAC(27,3) MAC(28,0) MAC(29,1) MAC(30,2) MAC(31,3)

// ---- scan kernel: 1 block, 64 threads ---------------------------------------
// Lane l owns gate rows r0 = l (i rows 0..31 / f rows 32..63) and
// r1 = 64+l (g rows 64..95 / o rows 96..127).
// Weights/biases prescaled by -log2(e) (g rows by -2*log2(e)) so
// sigmoid = rcp(1+exp2(acc)), tanh(g) = 2*rcp(1+exp2(acc))-1.
// Cell state kept as c2 = -2*log2(e)*c so tanh(c) = 2*rcp(1+exp2(c2))-1.
template <bool STORE_HS>
__global__ __launch_bounds__(64, 1)
__attribute__((amdgpu_waves_per_eu(1, 1)))  // RA: target exactly 1 wave/EU -> keep 72 values live
void lstm_scan(
    const float* __restrict__ x,      // [T,3]
    const float* __restrict__ W_ih,   // [128,3]
    const float* __restrict__ W_hh,   // [128,32]
    const float* __restrict__ b_ih,   // [128]
    const float* __restrict__ b_hh,   // [128]
    const float* __restrict__ W_lin,  // [1,32]  (fallback path only)
    const float* __restrict__ b_lin,  // [1]
    float* __restrict__ hs,           // ws: [T/4][32] float4   (STORE_HS)
    float* __restrict__ out)          // [T]                    (!STORE_HS)
{
    const int l = threadIdx.x;        // 0..63
    const bool lo = (l < 32);
    const int r0 = l;
    const int r1 = 64 + l;
    const float s0 = -L2E;
    const float s1 = lo ? KN2 : -L2E;
    const float m1 = lo ? 2.0f : 1.0f;   // tanh(g) = 2*sig-1 on lo lanes
    const float d1 = lo ? -1.0f : 0.0f;

    REP32(DECLW)
    REP32(LOADW)

    float wi00 = W_ih[r0 * 3 + 0] * s0, wi01 = W_ih[r0 * 3 + 1] * s0,
          wi02 = W_ih[r0 * 3 + 2] * s0;
    float wi10 = W_ih[r1 * 3 + 0] * s1, wi11 = W_ih[r1 * 3 + 1] * s1,
          wi12 = W_ih[r1 * 3 + 2] * s1;
    float bb0 = (b_ih[r0] + b_hh[r0]) * s0;
    float bb1 = (b_ih[r1] + b_hh[r1]) * s1;

    // fallback-path constants
    const float wl2 = STORE_HS ? 0.0f : (0.5f * W_lin[l & 31]);
    const float bl = STORE_HS ? 0.0f : b_lin[0];

    float h = 0.0f, c2 = 0.0f;        // c2 = -2*log2e * c ; c0 = 0
    float hh0 = 0.0f, hh1 = 0.0f, hh2 = 0.0f;
    float4* hs4 = (float4*)hs;

    // x double-buffer: lane u holds x[t0+u][0..2]
    float xa, xb, xc;
    {
        const float* xp = x + l * 3;
        xa = xp[0]; xb = xp[1]; xc = xp[2];
    }

    for (int t0 = 0; t0 < T_LEN; t0 += 64) {
        PIN_ALL   // zero-instruction: forces the 72 preloaded scalars VGPR-resident

        int tn = t0 + 64;
        if (tn >= T_LEN) tn = 0;      // harmless dummy prefetch on last block
        const float* xp = x + (tn + l) * 3;
        float xna = xp[0], xnb = xp[1], xnc = xp[2];

#pragma unroll 4
        for (int u = 0; u < 64; ++u) {
            // x contribution, spread across the 4 accumulators
            const float xs0 = rl_f(xa, u), xs1 = rl_f(xb, u), xs2 = rl_f(xc, u);
            float acc0_0 = fmaf(wi00, xs0, bb0);
            float acc0_1 = wi01 * xs1;
            float acc0_2 = wi02 * xs2;
            float acc0_3 = 0.0f;
            float acc1_0 = fmaf(wi10, xs0, bb1);
            float acc1_1 = wi11 * xs1;
            float acc1_2 = wi12 * xs2;
            float acc1_3 = 0.0f;

            MATVEC

            const float acc0 = (acc0_0 + acc0_1) + (acc0_2 + acc0_3);
            const float acc1 = (acc1_0 + acc1_1) + (acc1_2 + acc1_3);

            // activations
            const float a0 = frcp(1.0f + FEXP2(acc0));   // sigmoid(i) | sigmoid(f)
            const float rr = frcp(1.0f + FEXP2(acc1));
            const float a1 = fmaf(rr, m1, d1);           // tanh(g) | sigmoid(o)

            // cross-half exchange (VALU permlane, not LDS)
            const float sa0 = swap32(a0);
            const float sa1 = swap32(a1);
            const float f_ = lo ? sa0 : a0;
            const float i_ = lo ? a0 : sa0;
            const float g_ = lo ? a1 : sa1;
            const float o_ = lo ? sa1 : a1;

            const float igK = (i_ * KN2) * g_;
            c2 = fmaf(f_, c2, igK);
            const float tc = fmaf(frcp(1.0f + FEXP2(c2)), 2.0f, -1.0f);  // tanh(c)
            h = o_ * tc;              // lanes l and l+32 both hold h[l&31]

            if (STORE_HS) {
                const int ph = u & 3;
                if (ph == 0) hh0 = h;
                else if (ph == 1) hh1 = h;
                else if (ph == 2) hh2 = h;
                else if (lo) {
                    const int t4 = (t0 + u) >> 2;
                    hs4[t4 * 32 + l] = make_float4(hh0, hh1, hh2, h);
                }
            } else {
                float p = h * wl2;
                p += __shfl_xor(p, 1, 64);
                p += __shfl_xor(p, 2, 64);
                p += __shfl_xor(p, 4, 64);
                p += __shfl_xor(p, 8, 64);
                p += __shfl_xor(p, 16, 64);
                p += __shfl_xor(p, 32, 64);
                if (l == 0) out[t0 + u] = p + bl;
            }
        }

        xa = xna; xb = xnb; xc = xnc;
    }
}

// ---- output GEMV: out[t] = b_lin + sum_j W_lin[j] * h[t][j] ------------------
__global__ __launch_bounds__(256) void lstm_out(
    const float* __restrict__ hs, const float* __restrict__ W_lin,
    const float* __restrict__ b_lin, float* __restrict__ out)
{
    const int t = blockIdx.x * blockDim.x + threadIdx.x;
    if (t >= T_LEN) return;
    const int t4 = t >> 2, ph = t & 3;
    const float* base = hs + (size_t)t4 * 128 + ph;
    float acc = b_lin[0];
#pragma unroll
    for (int j = 0; j < HID; ++j) acc = fmaf(W_lin[j], base[j * 4], acc);
    out[t] = acc;
}

extern "C" void kernel_launch(void* const* d_in, const int* in_sizes, int n_in,
                              void* d_out, int out_size, void* d_ws, size_t ws_size,
                              hipStream_t stream) {
    const float* x = (const float*)d_in[0];
    const float* W_ih = (const float*)d_in[1];
    const float* W_hh = (const float*)d_in[2];
    const float* b_ih = (const float*)d_in[3];
    const float* b_hh = (const float*)d_in[4];
    const float* W_lin = (const float*)d_in[5];
    const float* b_lin = (const float*)d_in[6];
    float* out = (float*)d_out;

    const size_t hs_bytes = (size_t)(T_LEN / 4) * 32 * sizeof(float4);  // 32 MiB
    if (ws_size >= hs_bytes) {
        float* hs = (float*)d_ws;
        hipLaunchKernelGGL((lstm_scan<true>), dim3(1), dim3(64), 0, stream,
                           x, W_ih, W_hh, b_ih, b_hh, W_lin, b_lin, hs, out);
        hipLaunchKernelGGL(lstm_out, dim3(T_LEN / 256), dim3(256), 0, stream,
                           hs, W_lin, b_lin, out);
    } else {
        hipLaunchKernelGGL((lstm_scan<false>), dim3(1), dim3(64), 0, stream,
                           x, W_ih, W_hh, b_ih, b_hh, W_lin, b_lin, nullptr, out);
    }
}

// Round 4
// 61559.229 us; speedup vs baseline: 1.6264x; 1.0116x over previous
//
#include <hip/hip_runtime.h>
#include <hip/hip_fp16.h>

#define T_LEN 262144
#define HID 32

// ---- tiny intrinsic wrappers -------------------------------------------------
__device__ __forceinline__ float rl_f(float v, int lane) {
    return __int_as_float(__builtin_amdgcn_readlane(__float_as_int(v), lane));
}

#if defined(__has_builtin)
#if __has_builtin(__builtin_amdgcn_exp2f)
#define FEXP2(x) __builtin_amdgcn_exp2f(x)
#endif
#endif
#ifndef FEXP2
#define FEXP2(x) exp2f(x)
#endif

__device__ __forceinline__ float frcp(float x) { return __builtin_amdgcn_rcpf(x); }

#define L2E 1.4426950408889634f
#define KN2 (-2.0f * L2E)

typedef unsigned int uint2_ev __attribute__((ext_vector_type(2)));

// value held by lane (l ^ 32) — VALU permlane on gfx950, LDS-shuffle fallback
__device__ __forceinline__ float swap32(float v) {
#if defined(__has_builtin) && __has_builtin(__builtin_amdgcn_permlane32_swap)
    uint2_ev r = __builtin_amdgcn_permlane32_swap(__float_as_uint(v),
                                                  __float_as_uint(v), false, false);
    return __uint_as_float((threadIdx.x & 32) ? r.x : r.y);
#else
    return __shfl_xor(v, 32, 64);
#endif
}

// ---- repetition macros: named scalar weights --------------------------------
#define REP32(M) M(0) M(1) M(2) M(3) M(4) M(5) M(6) M(7) \
                 M(8) M(9) M(10) M(11) M(12) M(13) M(14) M(15) \
                 M(16) M(17) M(18) M(19) M(20) M(21) M(22) M(23) \
                 M(24) M(25) M(26) M(27) M(28) M(29) M(30) M(31)

#define DECLW(j) float w0_##j, w1_##j;
#define LOADW(j) w0_##j = W_hh[r0 * HID + j] * s0; \
                 w1_##j = W_hh[r1 * HID + j] * s1;

// Zero-instruction register pin: "+v" makes each value an asm output, so the
// compiler cannot re-derive it from memory. With the raised VGPR budget
// (see LDS guard + waves_per_eu below) the RA keeps them resident.
#define PIN8(a,b,c,d,e,f,g,h_) \
    asm("" : "+v"(a), "+v"(b), "+v"(c), "+v"(d), \
             "+v"(e), "+v"(f), "+v"(g), "+v"(h_));
#define PIN_W0_A PIN8(w0_0,w0_1,w0_2,w0_3,w0_4,w0_5,w0_6,w0_7)
#define PIN_W0_B PIN8(w0_8,w0_9,w0_10,w0_11,w0_12,w0_13,w0_14,w0_15)
#define PIN_W0_C PIN8(w0_16,w0_17,w0_18,w0_19,w0_20,w0_21,w0_22,w0_23)
#define PIN_W0_D PIN8(w0_24,w0_25,w0_26,w0_27,w0_28,w0_29,w0_30,w0_31)
#define PIN_W1_A PIN8(w1_0,w1_1,w1_2,w1_3,w1_4,w1_5,w1_6,w1_7)
#define PIN_W1_B PIN8(w1_8,w1_9,w1_10,w1_11,w1_12,w1_13,w1_14,w1_15)
#define PIN_W1_C PIN8(w1_16,w1_17,w1_18,w1_19,w1_20,w1_21,w1_22,w1_23)
#define PIN_W1_D PIN8(w1_24,w1_25,w1_26,w1_27,w1_28,w1_29,w1_30,w1_31)
#define PIN_ALL PIN_W0_A PIN_W0_B PIN_W0_C PIN_W0_D \
                PIN_W1_A PIN_W1_B PIN_W1_C PIN_W1_D \
                PIN8(wi00,wi01,wi02,wi10,wi11,wi12,bb0,bb1)

// one MAC pair, round-robin over 4 accumulators (breaks the serial FMA chain)
#define MAC(j, A) { const float hj_##j = rl_f(h, j); \
                    acc0_##A = fmaf(w0_##j, hj_##j, acc0_##A); \
                    acc1_##A = fmaf(w1_##j, hj_##j, acc1_##A); }

#define MATVEC \
    MAC(0,0) MAC(1,1) MAC(2,2) MAC(3,3)  MAC(4,0) MAC(5,1) MAC(6,2) MAC(7,3) \
    MAC(8,0) MAC(9,1) MAC(10,2) MAC(11,3) MAC(12,0) MAC(13,1) MAC(14,2) MAC(15,3) \
    MAC(16,0) MAC(17,1) MAC(18,2) MAC(19,3) MAC(20,0) MAC(21,1) MAC(22,2) MAC(23,3) \
    MAC(24,0) MAC(25,1) MAC(26,2) MAC(27,3) MAC(28,0) MAC(29,1) MAC(30,2) MAC(31,3)

// ---- scan kernel: 1 block, 64 threads ---------------------------------------
// Lane l owns gate rows r0 = l (i rows 0..31 / f rows 32..63) and
// r1 = 64+l (g rows 64..95 / o rows 96..127).
// Weights/biases prescaled by -log2(e) (g rows by -2*log2(e)) so
// sigmoid = rcp(1+exp2(acc)), tanh(g) = 2*rcp(1+exp2(acc))-1.
// Cell state kept as c2 = -2*log2(e)*c so tanh(c) = 2*rcp(1+exp2(c2))-1.
//
// NOTE: no __launch_bounds__ — its HIP expansion emits a competing
// amdgpu-waves-per-eu min-bound that kept the RA's VGPR budget at ~64 and
// forced the 64 weight scalars to spill to scratch (observed VGPR_Count=68
// in r3). Raw attributes + a 64 KiB LDS guard cap occupancy at ~1 wave/EU,
// raising the budget to ~512 VGPRs so the weights stay register-resident.
template <bool STORE_HS>
__global__
__attribute__((amdgpu_flat_work_group_size(64, 64), amdgpu_waves_per_eu(1, 1)))
void lstm_scan(
    const float* __restrict__ x,      // [T,3]
    const float* __restrict__ W_ih,   // [128,3]
    const float* __restrict__ W_hh,   // [128,32]
    const float* __restrict__ b_ih,   // [128]
    const float* __restrict__ b_hh,   // [128]
    const float* __restrict__ W_lin,  // [1,32]  (fallback path only)
    const float* __restrict__ b_lin,  // [1]
    float* __restrict__ hs,           // ws: [T/4][32] float4   (STORE_HS)
    float* __restrict__ out)          // [T]                    (!STORE_HS)
{
    // Occupancy limiter: 64 KiB static LDS -> max 2 workgroups/CU -> RA sees
    // ~1 wave/EU and gets the full VGPR file. One volatile store keeps it.
    __shared__ float lds_guard[16384];
    ((volatile float*)lds_guard)[threadIdx.x] = 0.0f;

    const int l = threadIdx.x;        // 0..63
    const bool lo = (l < 32);
    const int r0 = l;
    const int r1 = 64 + l;
    const float s0 = -L2E;
    const float s1 = lo ? KN2 : -L2E;
    const float m1 = lo ? 2.0f : 1.0f;   // tanh(g) = 2*sig-1 on lo lanes
    const float d1 = lo ? -1.0f : 0.0f;

    REP32(DECLW)
    REP32(LOADW)

    float wi00 = W_ih[r0 * 3 + 0] * s0, wi01 = W_ih[r0 * 3 + 1] * s0,
          wi02 = W_ih[r0 * 3 + 2] * s0;
    float wi10 = W_ih[r1 * 3 + 0] * s1, wi11 = W_ih[r1 * 3 + 1] * s1,
          wi12 = W_ih[r1 * 3 + 2] * s1;
    float bb0 = (b_ih[r0] + b_hh[r0]) * s0;
    float bb1 = (b_ih[r1] + b_hh[r1]) * s1;

    // fallback-path constants
    const float wl2 = STORE_HS ? 0.0f : (0.5f * W_lin[l & 31]);
    const float bl = STORE_HS ? 0.0f : b_lin[0];

    float h = 0.0f, c2 = 0.0f;        // c2 = -2*log2e * c ; c0 = 0
    float hh0 = 0.0f, hh1 = 0.0f, hh2 = 0.0f;
    float4* hs4 = (float4*)hs;

    // x double-buffer: lane u holds x[t0+u][0..2]
    float xa, xb, xc;
    {
        const float* xp = x + l * 3;
        xa = xp[0]; xb = xp[1]; xc = xp[2];
    }

    for (int t0 = 0; t0 < T_LEN; t0 += 64) {
        PIN_ALL   // zero-instruction: keeps the 72 preloaded scalars VGPR-resident

        int tn = t0 + 64;
        if (tn >= T_LEN) tn = 0;      // harmless dummy prefetch on last block
        const float* xp = x + (tn + l) * 3;
        float xna = xp[0], xnb = xp[1], xnc = xp[2];

#pragma unroll 4
        for (int u = 0; u < 64; ++u) {
            // x contribution, spread across the 4 accumulators
            const float xs0 = rl_f(xa, u), xs1 = rl_f(xb, u), xs2 = rl_f(xc, u);
            float acc0_0 = fmaf(wi00, xs0, bb0);
            float acc0_1 = wi01 * xs1;
            float acc0_2 = wi02 * xs2;
            float acc0_3 = 0.0f;
            float acc1_0 = fmaf(wi10, xs0, bb1);
            float acc1_1 = wi11 * xs1;
            float acc1_2 = wi12 * xs2;
            float acc1_3 = 0.0f;

            MATVEC

            const float acc0 = (acc0_0 + acc0_1) + (acc0_2 + acc0_3);
            const float acc1 = (acc1_0 + acc1_1) + (acc1_2 + acc1_3);

            // activations
            const float a0 = frcp(1.0f + FEXP2(acc0));   // sigmoid(i) | sigmoid(f)
            const float rr = frcp(1.0f + FEXP2(acc1));
            const float a1 = fmaf(rr, m1, d1);           // tanh(g) | sigmoid(o)

            // cross-half exchange (VALU permlane, not LDS)
            const float sa0 = swap32(a0);
            const float sa1 = swap32(a1);
            const float f_ = lo ? sa0 : a0;
            const float i_ = lo ? a0 : sa0;
            const float g_ = lo ? a1 : sa1;
            const float o_ = lo ? sa1 : a1;

            const float igK = (i_ * KN2) * g_;
            c2 = fmaf(f_, c2, igK);
            const float tc = fmaf(frcp(1.0f + FEXP2(c2)), 2.0f, -1.0f);  // tanh(c)
            h = o_ * tc;              // lanes l and l+32 both hold h[l&31]

            if (STORE_HS) {
                const int ph = u & 3;
                if (ph == 0) hh0 = h;
                else if (ph == 1) hh1 = h;
                else if (ph == 2) hh2 = h;
                else if (lo) {
                    const int t4 = (t0 + u) >> 2;
                    hs4[t4 * 32 + l] = make_float4(hh0, hh1, hh2, h);
                }
            } else {
                float p = h * wl2;
                p += __shfl_xor(p, 1, 64);
                p += __shfl_xor(p, 2, 64);
                p += __shfl_xor(p, 4, 64);
                p += __shfl_xor(p, 8, 64);
                p += __shfl_xor(p, 16, 64);
                p += __shfl_xor(p, 32, 64);
                if (l == 0) out[t0 + u] = p + bl;
            }
        }

        xa = xna; xb = xnb; xc = xnc;
    }
}

// ---- output GEMV: out[t] = b_lin + sum_j W_lin[j] * h[t][j] ------------------
__global__ __launch_bounds__(256) void lstm_out(
    const float* __restrict__ hs, const float* __restrict__ W_lin,
    const float* __restrict__ b_lin, float* __restrict__ out)
{
    const int t = blockIdx.x * blockDim.x + threadIdx.x;
    if (t >= T_LEN) return;
    const int t4 = t >> 2, ph = t & 3;
    const float* base = hs + (size_t)t4 * 128 + ph;
    float acc = b_lin[0];
#pragma unroll
    for (int j = 0; j < HID; ++j) acc = fmaf(W_lin[j], base[j * 4], acc);
    out[t] = acc;
}

extern "C" void kernel_launch(void* const* d_in, const int* in_sizes, int n_in,
                              void* d_out, int out_size, void* d_ws, size_t ws_size,
                              hipStream_t stream) {
    const float* x = (const float*)d_in[0];
    const float* W_ih = (const float*)d_in[1];
    const float* W_hh = (const float*)d_in[2];
    const float* b_ih = (const float*)d_in[3];
    const float* b_hh = (const float*)d_in[4];
    const float* W_lin = (const float*)d_in[5];
    const float* b_lin = (const float*)d_in[6];
    float* out = (float*)d_out;

    const size_t hs_bytes = (size_t)(T_LEN / 4) * 32 * sizeof(float4);  // 32 MiB
    if (ws_size >= hs_bytes) {
        float* hs = (float*)d_ws;
        hipLaunchKernelGGL((lstm_scan<true>), dim3(1), dim3(64), 0, stream,
                           x, W_ih, W_hh, b_ih, b_hh, W_lin, b_lin, hs, out);
        hipLaunchKernelGGL(lstm_out, dim3(T_LEN / 256), dim3(256), 0, stream,
                           hs, W_lin, b_lin, out);
    } else {
        hipLaunchKernelGGL((lstm_scan<false>), dim3(1), dim3(64), 0, stream,
                           x, W_ih, W_hh, b_ih, b_hh, W_lin, b_lin, nullptr, out);
    }
}

// Round 5
// 54010.010 us; speedup vs baseline: 1.8537x; 1.1398x over previous
//
#include <hip/hip_runtime.h>
#include <hip/hip_fp16.h>

#define T_LEN 262144
#define HID 32

typedef float f32x2 __attribute__((ext_vector_type(2)));
typedef unsigned int uint2_ev __attribute__((ext_vector_type(2)));

// ---- tiny intrinsic wrappers -------------------------------------------------
__device__ __forceinline__ float rl_f(float v, int lane) {
    return __int_as_float(__builtin_amdgcn_readlane(__float_as_int(v), lane));
}

#if defined(__has_builtin)
#if __has_builtin(__builtin_amdgcn_exp2f)
#define FEXP2(x) __builtin_amdgcn_exp2f(x)
#endif
#endif
#ifndef FEXP2
#define FEXP2(x) exp2f(x)
#endif

__device__ __forceinline__ float frcp(float x) { return __builtin_amdgcn_rcpf(x); }

#if defined(__has_builtin)
#if __has_builtin(__builtin_amdgcn_sched_barrier)
#define SCHED_FENCE() __builtin_amdgcn_sched_barrier(0)
#endif
#endif
#ifndef SCHED_FENCE
#define SCHED_FENCE()
#endif

#define L2E 1.4426950408889634f
#define KN2 (-2.0f * L2E)

// value held by lane (l ^ 32) — VALU permlane on gfx950, LDS-shuffle fallback
__device__ __forceinline__ float swap32(float v) {
#if defined(__has_builtin) && __has_builtin(__builtin_amdgcn_permlane32_swap)
    uint2_ev r = __builtin_amdgcn_permlane32_swap(__float_as_uint(v),
                                                  __float_as_uint(v), false, false);
    return __uint_as_float((threadIdx.x & 32) ? r.x : r.y);
#else
    return __shfl_xor(v, 32, 64);
#endif
}

// ---- repetition macros -------------------------------------------------------
#define REP32(M) M(0) M(1) M(2) M(3) M(4) M(5) M(6) M(7) \
                 M(8) M(9) M(10) M(11) M(12) M(13) M(14) M(15) \
                 M(16) M(17) M(18) M(19) M(20) M(21) M(22) M(23) \
                 M(24) M(25) M(26) M(27) M(28) M(29) M(30) M(31)

#define DECLW(j) f32x2 w_##j;
#define LOADW(j) w_##j = (f32x2){W_hh[r0 * HID + j] * s0, W_hh[r1 * HID + j] * s1};

// Zero-instruction register pin (see r3/r4 notes): with the raised VGPR budget
// these keep the 32 weight pairs + 8 scalars loop-carried in VGPRs.
#define PIN8(a,b,c,d,e,f,g,h_) \
    asm("" : "+v"(a), "+v"(b), "+v"(c), "+v"(d), \
             "+v"(e), "+v"(f), "+v"(g), "+v"(h_));
#define PIN_ALL \
    PIN8(w_0,w_1,w_2,w_3,w_4,w_5,w_6,w_7) \
    PIN8(w_8,w_9,w_10,w_11,w_12,w_13,w_14,w_15) \
    PIN8(w_16,w_17,w_18,w_19,w_20,w_21,w_22,w_23) \
    PIN8(w_24,w_25,w_26,w_27,w_28,w_29,w_30,w_31) \
    PIN8(wi00,wi01,wi02,wi10,wi11,wi12,bb0,bb1)

// h broadcasts read the HI half (lanes 32..63 hold the valid h)
#define RLH(j) const float hj_##j = rl_f(h, 32 + j);
#define RLH_A RLH(0) RLH(1) RLH(2) RLH(3) RLH(4) RLH(5) RLH(6) RLH(7) \
              RLH(8) RLH(9) RLH(10) RLH(11) RLH(12) RLH(13) RLH(14) RLH(15)
#define RLH_B RLH(16) RLH(17) RLH(18) RLH(19) RLH(20) RLH(21) RLH(22) RLH(23) \
              RLH(24) RLH(25) RLH(26) RLH(27) RLH(28) RLH(29) RLH(30) RLH(31)

// packed MAC (compiler may form v_pk_fma_f32; scalarized is equally correct)
#define MAC2(j, A) { f32x2 hj2_##j = {hj_##j, hj_##j}; \
                     A = __builtin_elementwise_fma(w_##j, hj2_##j, A); }
#define MAC_A MAC2(0,A0) MAC2(1,A1) MAC2(2,A0) MAC2(3,A1) \
              MAC2(4,A0) MAC2(5,A1) MAC2(6,A0) MAC2(7,A1) \
              MAC2(8,A0) MAC2(9,A1) MAC2(10,A0) MAC2(11,A1) \
              MAC2(12,A0) MAC2(13,A1) MAC2(14,A0) MAC2(15,A1)
#define MAC_B MAC2(16,A0) MAC2(17,A1) MAC2(18,A0) MAC2(19,A1) \
              MAC2(20,A0) MAC2(21,A1) MAC2(22,A0) MAC2(23,A1) \
              MAC2(24,A0) MAC2(25,A1) MAC2(26,A0) MAC2(27,A1) \
              MAC2(28,A0) MAC2(29,A1) MAC2(30,A0) MAC2(31,A1)

// ---- scan kernel: 1 block, 64 threads ---------------------------------------
// Lane l owns gate rows r0 = l (i rows 0..31 / f rows 32..63) and
// r1 = 64+l (g rows 64..95 / o rows 96..127).
// Row-r0 weights prescaled by -log2e (sigmoid); row-r1 by -2log2e on lo lanes
// (tanh g) and -log2e on hi (sigmoid o). KN2 is folded into the g activation:
// a1(lo) = KN2*tanh(g) = fma(sig, 2*KN2, -KN2), so c2 = f*c2 + i*a1 directly,
// where c2 = KN2*c and tanh(c) = 2*rcp(1+exp2(c2))-1.
// h is computed valid on HI lanes only (o lives there); broadcasts read 32+j.
template <bool STORE_HS>
__global__
__attribute__((amdgpu_flat_work_group_size(64, 64), amdgpu_waves_per_eu(1, 1)))
void lstm_scan(
    const float* __restrict__ x,      // [T,3]
    const float* __restrict__ W_ih,   // [128,3]
    const float* __restrict__ W_hh,   // [128,32]
    const float* __restrict__ b_ih,   // [128]
    const float* __restrict__ b_hh,   // [128]
    const float* __restrict__ W_lin,  // [1,32]  (fallback path only)
    const float* __restrict__ b_lin,  // [1]
    float* __restrict__ hs,           // ws: [T/4][32] float4   (STORE_HS)
    float* __restrict__ out)          // [T]                    (!STORE_HS)
{
    // Occupancy limiter: 64 KiB static LDS -> RA sees ~1 wave/EU -> full VGPR
    // budget -> the 64 weight floats stay register-resident (r4: VGPR 68->132).
    __shared__ float lds_guard[16384];
    ((volatile float*)lds_guard)[threadIdx.x] = 0.0f;

    const int l = threadIdx.x;        // 0..63
    const bool lo = (l < 32);
    const int r0 = l;
    const int r1 = 64 + l;
    const float s0 = -L2E;
    const float s1 = lo ? KN2 : -L2E;
    const float m1 = lo ? (2.0f * KN2) : 1.0f;   // a1 = fma(sig, m1, d1)
    const float d1 = lo ? (-KN2) : 0.0f;

    REP32(DECLW)
    REP32(LOADW)

    float wi00 = W_ih[r0 * 3 + 0] * s0, wi01 = W_ih[r0 * 3 + 1] * s0,
          wi02 = W_ih[r0 * 3 + 2] * s0;
    float wi10 = W_ih[r1 * 3 + 0] * s1, wi11 = W_ih[r1 * 3 + 1] * s1,
          wi12 = W_ih[r1 * 3 + 2] * s1;
    float bb0 = (b_ih[r0] + b_hh[r0]) * s0;
    float bb1 = (b_ih[r1] + b_hh[r1]) * s1;

    // fallback-path constants (h valid on hi lanes only)
    const float wl = (STORE_HS || lo) ? 0.0f : W_lin[l & 31];
    const float bl = STORE_HS ? 0.0f : b_lin[0];

    float h = 0.0f, c2 = 0.0f;        // c2 = KN2 * c ; c0 = 0
    float hh0 = 0.0f, hh1 = 0.0f, hh2 = 0.0f;
    float4* hs4 = (float4*)hs;

    // x double-buffer: lane u holds x[t0+u][0..2]
    float xa, xb, xc;
    {
        const float* xp = x + l * 3;
        xa = xp[0]; xb = xp[1]; xc = xp[2];
    }

    for (int t0 = 0; t0 < T_LEN; t0 += 64) {
        PIN_ALL

        int tn = t0 + 64;
        if (tn >= T_LEN) tn = 0;      // harmless dummy prefetch on last block
        const float* xp = x + (tn + l) * 3;
        float xna = xp[0], xnb = xp[1], xnc = xp[2];

#pragma unroll 4
        for (int u = 0; u < 64; ++u) {
            // ---- broadcast batch 1: x row + first 16 h values --------------
            // (batched back-to-back: no VALU->SGPR->VALU hazard stalls; the
            //  first consumer runs >=16 instructions after the producer)
            const float xs0 = rl_f(xa, u), xs1 = rl_f(xb, u), xs2 = rl_f(xc, u);
            RLH_A
            SCHED_FENCE();

            // ---- x contribution + MAC batch 1 ------------------------------
            f32x2 A0 = {fmaf(wi00, xs0, bb0), fmaf(wi10, xs0, bb1)};
            f32x2 A1 = {fmaf(wi01, xs1, wi02 * xs2),
                        fmaf(wi11, xs1, wi12 * xs2)};
            MAC_A
            SCHED_FENCE();

            // ---- broadcast batch 2 + MAC batch 2 ---------------------------
            RLH_B
            SCHED_FENCE();
            MAC_B

            const f32x2 S = A0 + A1;

            // ---- activations ----------------------------------------------
            const float a0 = frcp(1.0f + FEXP2(S.x));   // sigmoid(i) | sigmoid(f)
            const float rr = frcp(1.0f + FEXP2(S.y));
            const float a1 = fmaf(rr, m1, d1);          // KN2*tanh(g) | sigmoid(o)

            // ---- single cross-half exchange -------------------------------
            const float igK = a0 * a1;                  // lo: KN2*i*g ; hi: junk
            const float v_ = lo ? igK : a0;             // lo sends igK, hi sends f
            const float sw = swap32(v_);
            const float f_ = lo ? sw : a0;
            const float iK = lo ? igK : sw;

            c2 = fmaf(f_, c2, iK);
            const float tc = fmaf(frcp(1.0f + FEXP2(c2)), 2.0f, -1.0f);  // tanh(c)
            h = a1 * tc;                                // valid on HI lanes (a1=o)

            if (STORE_HS) {
                const int ph = u & 3;
                if (ph == 0) hh0 = h;
                else if (ph == 1) hh1 = h;
                else if (ph == 2) hh2 = h;
                else if (!lo) {
                    const int t4 = (t0 + u) >> 2;
                    hs4[t4 * 32 + (l - 32)] = make_float4(hh0, hh1, hh2, h);
                }
            } else {
                float p = h * wl;                       // lo lanes contribute 0
                p += __shfl_xor(p, 1, 64);
                p += __shfl_xor(p, 2, 64);
                p += __shfl_xor(p, 4, 64);
                p += __shfl_xor(p, 8, 64);
                p += __shfl_xor(p, 16, 64);
                p += __shfl_xor(p, 32, 64);
                if (l == 0) out[t0 + u] = p + bl;
            }
        }

        xa = xna; xb = xnb; xc = xnc;
    }
}

// ---- output GEMV: out[t] = b_lin + sum_j W_lin[j] * h[t][j] ------------------
__global__ __launch_bounds__(256) void lstm_out(
    const float* __restrict__ hs, const float* __restrict__ W_lin,
    const float* __restrict__ b_lin, float* __restrict__ out)
{
    const int t = blockIdx.x * blockDim.x + threadIdx.x;
    if (t >= T_LEN) return;
    const int t4 = t >> 2, ph = t & 3;
    const float* base = hs + (size_t)t4 * 128 + ph;
    float acc = b_lin[0];
#pragma unroll
    for (int j = 0; j < HID; ++j) acc = fmaf(W_lin[j], base[j * 4], acc);
    out[t] = acc;
}

extern "C" void kernel_launch(void* const* d_in, const int* in_sizes, int n_in,
                              void* d_out, int out_size, void* d_ws, size_t ws_size,
                              hipStream_t stream) {
    const float* x = (const float*)d_in[0];
    const float* W_ih = (const float*)d_in[1];
    const float* W_hh = (const float*)d_in[2];
    const float* b_ih = (const float*)d_in[3];
    const float* b_hh = (const float*)d_in[4];
    const float* W_lin = (const float*)d_in[5];
    const float* b_lin = (const float*)d_in[6];
    float* out = (float*)d_out;

    const size_t hs_bytes = (size_t)(T_LEN / 4) * 32 * sizeof(float4);  // 32 MiB
    if (ws_size >= hs_bytes) {
        float* hs = (float*)d_ws;
        hipLaunchKernelGGL((lstm_scan<true>), dim3(1), dim3(64), 0, stream,
                           x, W_ih, W_hh, b_ih, b_hh, W_lin, b_lin, hs, out);
        hipLaunchKernelGGL(lstm_out, dim3(T_LEN / 256), dim3(256), 0, stream,
                           hs, W_lin, b_lin, out);
    } else {
        hipLaunchKernelGGL((lstm_scan<false>), dim3(1), dim3(64), 0, stream,
                           x, W_ih, W_hh, b_ih, b_hh, W_lin, b_lin, nullptr, out);
    }
}

// Round 6
// 48469.031 us; speedup vs baseline: 2.0657x; 1.1143x over previous
//
#include <hip/hip_runtime.h>
#include <hip/hip_fp16.h>

#define T_LEN 262144
#define HID 32

typedef _Float16 half2_t __attribute__((ext_vector_type(2)));
typedef unsigned int uint2_ev __attribute__((ext_vector_type(2)));

// ---- tiny intrinsic wrappers -------------------------------------------------
__device__ __forceinline__ float rl_f(float v, int lane) {
    return __int_as_float(__builtin_amdgcn_readlane(__float_as_int(v), lane));
}
__device__ __forceinline__ int rl_i(int v, int lane) {
    return __builtin_amdgcn_readlane(v, lane);
}

#if defined(__has_builtin)
#if __has_builtin(__builtin_amdgcn_exp2f)
#define FEXP2(x) __builtin_amdgcn_exp2f(x)
#endif
#endif
#ifndef FEXP2
#define FEXP2(x) exp2f(x)
#endif

__device__ __forceinline__ float frcp(float x) { return __builtin_amdgcn_rcpf(x); }

#if defined(__has_builtin)
#if __has_builtin(__builtin_amdgcn_sched_barrier)
#define SCHED_FENCE() __builtin_amdgcn_sched_barrier(0)
#endif
#endif
#ifndef SCHED_FENCE
#define SCHED_FENCE()
#endif

// packed 2×f16 MAC with f32 accumulate (full-rate VOP3P v_dot2_f32_f16)
#if defined(__has_builtin) && __has_builtin(__builtin_amdgcn_fdot2)
#define FDOT2(a, b, c) __builtin_amdgcn_fdot2((a), (b), (c), false)
#else
#define FDOT2(a, b, c) fmaf((float)(a).x, (float)(b).x, \
                            fmaf((float)(a).y, (float)(b).y, (c)))
#endif

// neighbor value within quad (lane^1) — full-rate VALU DPP, LDS-swizzle fallback
__device__ __forceinline__ int quad_xor1(int v) {
#if defined(__has_builtin) && __has_builtin(__builtin_amdgcn_mov_dpp)
    return __builtin_amdgcn_mov_dpp(v, 0xB1 /*quad_perm [1,0,3,2]*/, 0xF, 0xF, true);
#else
    return __builtin_amdgcn_ds_swizzle(v, 0x041F);  // xor 1
#endif
}

#define L2E 1.4426950408889634f
#define KN2 (-2.0f * L2E)

// value held by lane (l ^ 32) — VALU permlane on gfx950, LDS-shuffle fallback
__device__ __forceinline__ float swap32(float v) {
#if defined(__has_builtin) && __has_builtin(__builtin_amdgcn_permlane32_swap)
    uint2_ev r = __builtin_amdgcn_permlane32_swap(__float_as_uint(v),
                                                  __float_as_uint(v), false, false);
    return __uint_as_float((threadIdx.x & 32) ? r.x : r.y);
#else
    return __shfl_xor(v, 32, 64);
#endif
}

// ---- repetition macros -------------------------------------------------------
#define REP16(M) M(0) M(1) M(2) M(3) M(4) M(5) M(6) M(7) \
                 M(8) M(9) M(10) M(11) M(12) M(13) M(14) M(15)

__device__ __forceinline__ unsigned int pack_f16(float a, float b) {
    unsigned short ua = __builtin_bit_cast(unsigned short, (_Float16)a);
    unsigned short ub = __builtin_bit_cast(unsigned short, (_Float16)b);
    return (unsigned int)ua | ((unsigned int)ub << 16);
}

// weight pair p: columns 2p,2p+1 of rows r0 / r1, prescaled then f16-packed
#define DECLW(p) unsigned int wp0_##p, wp1_##p;
#define LOADW(p) \
    wp0_##p = pack_f16(W_hh[r0 * HID + 2 * p] * s0, W_hh[r0 * HID + 2 * p + 1] * s0); \
    wp1_##p = pack_f16(W_hh[r1 * HID + 2 * p] * s1, W_hh[r1 * HID + 2 * p + 1] * s1);

// Zero-instruction register pin (r3/r4 lesson): with the LDS-guard-raised VGPR
// budget these keep the packed weights loop-carried in VGPRs.
#define PIN8(a,b,c,d,e,f,g,h_) \
    asm("" : "+v"(a), "+v"(b), "+v"(c), "+v"(d), \
             "+v"(e), "+v"(f), "+v"(g), "+v"(h_));
#define PIN_ALL \
    PIN8(wp0_0,wp0_1,wp0_2,wp0_3,wp0_4,wp0_5,wp0_6,wp0_7) \
    PIN8(wp0_8,wp0_9,wp0_10,wp0_11,wp0_12,wp0_13,wp0_14,wp0_15) \
    PIN8(wp1_0,wp1_1,wp1_2,wp1_3,wp1_4,wp1_5,wp1_6,wp1_7) \
    PIN8(wp1_8,wp1_9,wp1_10,wp1_11,wp1_12,wp1_13,wp1_14,wp1_15) \
    PIN8(wi00,wi01,wi02,wi10,wi11,wi12,bb0,bb1)

// broadcast packed h pair p from hi lane 32+2p (h2 valid on even lanes)
#define RLH(p) const int hp_##p = rl_i(h2, 32 + 2 * p);
// two dot2 per pair (rows r0,r1), alternating accumulators
#define MACP(p, A, B) { \
    const half2_t hh_##p = __builtin_bit_cast(half2_t, hp_##p); \
    A = FDOT2(__builtin_bit_cast(half2_t, wp0_##p), hh_##p, A); \
    B = FDOT2(__builtin_bit_cast(half2_t, wp1_##p), hh_##p, B); }

#define MAC_ALL \
    MACP(0,a0a,a1a) MACP(1,a0b,a1b) MACP(2,a0a,a1a) MACP(3,a0b,a1b) \
    MACP(4,a0a,a1a) MACP(5,a0b,a1b) MACP(6,a0a,a1a) MACP(7,a0b,a1b) \
    MACP(8,a0a,a1a) MACP(9,a0b,a1b) MACP(10,a0a,a1a) MACP(11,a0b,a1b) \
    MACP(12,a0a,a1a) MACP(13,a0b,a1b) MACP(14,a0a,a1a) MACP(15,a0b,a1b)

// ---- scan kernel: 1 block, 64 threads ---------------------------------------
// Lane l owns gate rows r0 = l (i rows 0..31 / f rows 32..63) and
// r1 = 64+l (g rows 64..95 / o rows 96..127).
// Row-r0 weights prescaled by -log2e (sigmoid); row-r1 by -2log2e on lo lanes
// (tanh g) and -log2e on hi (sigmoid o); then rounded to f16 and packed in
// column pairs. Recurrent matvec = 16 readlane broadcasts of packed-f16 h
// pairs + 32 v_dot2_f32_f16 (f32 accumulate). Cell state c2 = KN2*c (f32);
// tanh(c) = 2*rcp(1+exp2(c2))-1; a1(lo) = KN2*tanh(g) so c2 = f*c2 + i*a1.
// h is f32, valid on HI lanes; packed-f16 h pairs on even hi lanes.
template <bool STORE_HS>
__global__
__attribute__((amdgpu_flat_work_group_size(64, 64), amdgpu_waves_per_eu(1, 1)))
void lstm_scan(
    const float* __restrict__ x,      // [T,3]
    const float* __restrict__ W_ih,   // [128,3]
    const float* __restrict__ W_hh,   // [128,32]
    const float* __restrict__ b_ih,   // [128]
    const float* __restrict__ b_hh,   // [128]
    const float* __restrict__ W_lin,  // [1,32]  (fallback path only)
    const float* __restrict__ b_lin,  // [1]
    float* __restrict__ hs,           // ws: [T/4][32] float4   (STORE_HS)
    float* __restrict__ out)          // [T]                    (!STORE_HS)
{
    // Occupancy limiter: 64 KiB static LDS -> RA sees ~1 wave/EU -> full VGPR
    // budget -> weights stay register-resident (r4: VGPR 68->132 proved this).
    __shared__ float lds_guard[16384];
    ((volatile float*)lds_guard)[threadIdx.x] = 0.0f;

    const int l = threadIdx.x;        // 0..63
    const bool lo = (l < 32);
    const int r0 = l;
    const int r1 = 64 + l;
    const float s0 = -L2E;
    const float s1 = lo ? KN2 : -L2E;
    const float m1 = lo ? (2.0f * KN2) : 1.0f;   // a1 = fma(sig, m1, d1)
    const float d1 = lo ? (-KN2) : 0.0f;

    REP16(DECLW)
    REP16(LOADW)

    float wi00 = W_ih[r0 * 3 + 0] * s0, wi01 = W_ih[r0 * 3 + 1] * s0,
          wi02 = W_ih[r0 * 3 + 2] * s0;
    float wi10 = W_ih[r1 * 3 + 0] * s1, wi11 = W_ih[r1 * 3 + 1] * s1,
          wi12 = W_ih[r1 * 3 + 2] * s1;
    float bb0 = (b_ih[r0] + b_hh[r0]) * s0;
    float bb1 = (b_ih[r1] + b_hh[r1]) * s1;

    // fallback-path constants (h valid on hi lanes only)
    const float wl = (STORE_HS || lo) ? 0.0f : W_lin[l & 31];
    const float bl = STORE_HS ? 0.0f : b_lin[0];

    float h = 0.0f, c2 = 0.0f;        // c2 = KN2 * c ; c0 = 0
    int h2 = 0;                       // packed f16 {h[2p], h[2p+1]} on even lanes
    float hh0 = 0.0f, hh1 = 0.0f, hh2 = 0.0f;
    float4* hs4 = (float4*)hs;

    // x double-buffer: lane u holds x[t0+u][0..2]
    float xa, xb, xc;
    {
        const float* xp = x + l * 3;
        xa = xp[0]; xb = xp[1]; xc = xp[2];
    }

    for (int t0 = 0; t0 < T_LEN; t0 += 64) {
        PIN_ALL

        int tn = t0 + 64;
        if (tn >= T_LEN) tn = 0;      // harmless dummy prefetch on last block
        const float* xp = x + (tn + l) * 3;
        float xna = xp[0], xnb = xp[1], xnc = xp[2];

#pragma unroll 4
        for (int u = 0; u < 64; ++u) {
            // ---- broadcast batch: x row + 16 packed h pairs ----------------
            const float xs0 = rl_f(xa, u), xs1 = rl_f(xb, u), xs2 = rl_f(xc, u);
            REP16(RLH)
            SCHED_FENCE();

            // ---- x contribution + packed-f16 recurrent matvec --------------
            float a0a = fmaf(wi00, xs0, bb0);
            float a0b = fmaf(wi01, xs1, wi02 * xs2);
            float a1a = fmaf(wi10, xs0, bb1);
            float a1b = fmaf(wi11, xs1, wi12 * xs2);
            MAC_ALL

            const float S0 = a0a + a0b;
            const float S1 = a1a + a1b;

            // ---- activations ----------------------------------------------
            const float a0 = frcp(1.0f + FEXP2(S0));    // sigmoid(i) | sigmoid(f)
            const float rr = frcp(1.0f + FEXP2(S1));
            const float a1 = fmaf(rr, m1, d1);          // KN2*tanh(g) | sigmoid(o)

            // ---- single cross-half exchange -------------------------------
            const float igK = a0 * a1;                  // lo: KN2*i*g ; hi: junk
            const float v_ = lo ? igK : a0;             // lo sends igK, hi sends f
            const float sw = swap32(v_);
            const float f_ = lo ? sw : a0;
            const float iK = lo ? igK : sw;

            c2 = fmaf(f_, c2, iK);
            const float tc = fmaf(frcp(1.0f + FEXP2(c2)), 2.0f, -1.0f);  // tanh(c)
            h = a1 * tc;                                // valid on HI lanes (a1=o)

            // ---- rebuild packed-f16 h pairs (even lanes) -------------------
            const int hf = (int)(unsigned int)__builtin_bit_cast(
                unsigned short, (_Float16)h);
            const int nb = quad_xor1(hf);               // neighbor's f16(h)
            h2 = hf | (nb << 16);                       // {h[2p], h[2p+1]} on even

            if (STORE_HS) {
                const int ph = u & 3;
                if (ph == 0) hh0 = h;
                else if (ph == 1) hh1 = h;
                else if (ph == 2) hh2 = h;
                else if (!lo) {
                    const int t4 = (t0 + u) >> 2;
                    hs4[t4 * 32 + (l - 32)] = make_float4(hh0, hh1, hh2, h);
                }
            } else {
                float p = h * wl;                       // lo lanes contribute 0
                p += __shfl_xor(p, 1, 64);
                p += __shfl_xor(p, 2, 64);
                p += __shfl_xor(p, 4, 64);
                p += __shfl_xor(p, 8, 64);
                p += __shfl_xor(p, 16, 64);
                p += __shfl_xor(p, 32, 64);
                if (l == 0) out[t0 + u] = p + bl;
            }
        }

        xa = xna; xb = xnb; xc = xnc;
    }
}

// ---- output GEMV: out[t] = b_lin + sum_j W_lin[j] * h[t][j] ------------------
__global__ __launch_bounds__(256) void lstm_out(
    const float* __restrict__ hs, const float* __restrict__ W_lin,
    const float* __restrict__ b_lin, float* __restrict__ out)
{
    const int t = blockIdx.x * blockDim.x + threadIdx.x;
    if (t >= T_LEN) return;
    const int t4 = t >> 2, ph = t & 3;
    const float* base = hs + (size_t)t4 * 128 + ph;
    float acc = b_lin[0];
#pragma unroll
    for (int j = 0; j < HID; ++j) acc = fmaf(W_lin[j], base[j * 4], acc);
    out[t] = acc;
}

extern "C" void kernel_launch(void* const* d_in, const int* in_sizes, int n_in,
                              void* d_out, int out_size, void* d_ws, size_t ws_size,
                              hipStream_t stream) {
    const float* x = (const float*)d_in[0];
    const float* W_ih = (const float*)d_in[1];
    const float* W_hh = (const float*)d_in[2];
    const float* b_ih = (const float*)d_in[3];
    const float* b_hh = (const float*)d_in[4];
    const float* W_lin = (const float*)d_in[5];
    const float* b_lin = (const float*)d_in[6];
    float* out = (float*)d_out;

    const size_t hs_bytes = (size_t)(T_LEN / 4) * 32 * sizeof(float4);  // 32 MiB
    if (ws_size >= hs_bytes) {
        float* hs = (float*)d_ws;
        hipLaunchKernelGGL((lstm_scan<true>), dim3(1), dim3(64), 0, stream,
                           x, W_ih, W_hh, b_ih, b_hh, W_lin, b_lin, hs, out);
        hipLaunchKernelGGL(lstm_out, dim3(T_LEN / 256), dim3(256), 0, stream,
                           hs, W_lin, b_lin, out);
    } else {
        hipLaunchKernelGGL((lstm_scan<false>), dim3(1), dim3(64), 0, stream,
                           x, W_ih, W_hh, b_ih, b_hh, W_lin, b_lin, nullptr, out);
    }
}